// Round 25
// baseline (435.223 us; speedup 1.0000x reference)
//
#include <hip/hip_runtime.h>
#include <hip/hip_bf16.h>
#include <cstddef>
#include <cstdint>

typedef __bf16 bf16;
typedef __attribute__((ext_vector_type(8))) __bf16 bf16x8;
typedef __attribute__((ext_vector_type(4))) __bf16 bf16x4;
typedef __attribute__((ext_vector_type(4))) float f32x4;
typedef __attribute__((ext_vector_type(2))) float f32x2;

// ---------------------------------------------------------------------------
// Pipeline (9 launches):
//  Kp  fused prep: wm MLP -> wm_coff; tr_w1/2/3 -> w1b/w2b/w3b bf16 repacks
//  Kxp x NCHW fp32 -> xb NHWC bf16 + pooled/modulated t0b  [x-split 33KB LDS]
//  K3  MFMA conv 128->64 s1 p0 +bias+lrelu -> t1b NHWC bf16 (32,62,62,64)
//  K4  MFMA conv 64->64 s2 p0 +bias+lrelu -> t2b NHWC bf16 (32,30,30,64)
//  Ke  expert_w repack -> ewr[e][tap][co][cin] fp32 (294912 elems, 1152 blks)
//  K5  MFMA conv 64->64 s2 p0 +bias+lrelu -> t3 fp32 NCHW (32,64,14,14)
//  K6  fused heads (GAP trick) -> agg (32,4,128), katt (32,4)
//  K7  combine (coalesced ewr) + fold wm_coff -> wfinb bf16 [32][9][64][128]
//  K8  MFMA per-sample conv(xb, wfinb) p1 -> out fp32 NCHW (32,64,128,128)
// Conv template: r19 champion. NEW r25: K8's SWZY path maps BATCH to XCD
// (XCD = linear_bid%8 = bx%8; choose b with b%8==bx%8) so each XCD's 4MB L2
// caches only 4 batches' weights (588KB) instead of thrashing on all 32
// (4.7MB). A-loads (the latency bottleneck) become L2-resident.
// ---------------------------------------------------------------------------

// Fused prep: blocks [0,288) w1b repack, [288,432) w2b, [432,576) w3b,
// [576,608) wm embedding MLP (threads 0..127 active).
__global__ __launch_bounds__(256) void k_prep(
    const float* __restrict__ wm, const float* __restrict__ wm_w1,
    const float* __restrict__ wm_b1, const float* __restrict__ wm_w2,
    const float* __restrict__ wm_b2, float* __restrict__ coff,
    const float* __restrict__ tr_w1, bf16* __restrict__ w1b,
    const float* __restrict__ tr_w2, bf16* __restrict__ w2b,
    const float* __restrict__ tr_w3, bf16* __restrict__ w3b)
{
    const int blk = blockIdx.x;
    if (blk < 288) {
        int i = blk * 256 + threadIdx.x;             // 73728 exact
        int cin = i & 127, t2 = i >> 7, co = t2 & 63, tap = t2 >> 6;
        w1b[i] = (bf16)(tr_w1[((size_t)co * 128 + cin) * 9 + tap]);
    } else if (blk < 432) {
        int i = (blk - 288) * 256 + threadIdx.x;     // 36864 exact
        int cin = i & 63, co = (i >> 6) & 63, tap = i >> 12;
        w2b[i] = (bf16)(tr_w2[((size_t)co * 64 + cin) * 9 + tap]);
    } else if (blk < 576) {
        int i = (blk - 432) * 256 + threadIdx.x;     // 36864 exact
        int cin = i & 63, co = (i >> 6) & 63, tap = i >> 12;
        w3b[i] = (bf16)(tr_w3[((size_t)co * 64 + cin) * 9 + tap]);
    } else {
        const int b = blk - 576;                     // 32 blocks
        __shared__ float h[128];
        const int j = threadIdx.x;
        if (j < 128) {
            float acc = wm_b1[j];
            for (int k = 0; k < 32; ++k) acc += wm[b * 32 + k] * wm_w1[j * 32 + k];
            h[j] = acc >= 0.f ? acc : 0.2f * acc;    // slope 0.2
        }
        __syncthreads();
        if (j < 128) {
            float acc2 = wm_b2[j];
            for (int k = 0; k < 128; ++k) acc2 += h[k] * wm_w2[j * 128 + k];
            coff[b * 128 + j] = acc2;
        }
    }
}

// expert_w [e][co][cin][tap] -> ewr [e][tap][co][cin]; 294912 elements EXACT.
__global__ __launch_bounds__(256) void k_ewr(
    const float* __restrict__ expert_w, float* __restrict__ ewr)
{
    int i = blockIdx.x * 256 + threadIdx.x;          // 1152 blocks * 256 = 294912
    int cin = i & 127;
    int co  = (i >> 7) & 63;
    int et  = i >> 13;                               // e*9 + tap, in [0,36)
    int tap = et % 9;
    int e   = et / 9;
    ewr[i] = expert_w[(((size_t)e * 64 + co) * 128 + cin) * 9 + tap];
}

// Fused: x [b][c][y][x] fp32 -> xb [b][y][x][c] bf16 (row pair, x-half) AND
// t0b for that (row pair, x-half). Tile [2 rows][64 xp][128 c] = 32 KB LDS.
__global__ __launch_bounds__(256) void k_x2nhwc_pool(
    const float* __restrict__ x, const float* __restrict__ coff,
    bf16* __restrict__ xb, bf16* __restrict__ t0b)
{
    __shared__ bf16 t[2][64 * 128];      // 32 KB, [row][xp_local][c] swizzled
    __shared__ float cf[128];
    const int y2 = blockIdx.x >> 1, xh = blockIdx.x & 1, b = blockIdx.y;
    const int xbase = xh << 6;           // x offset of this half-tile
    if (threadIdx.x < 128) cf[threadIdx.x] = 0.25f * coff[b * 128 + threadIdx.x];
    const float* xp0 = x + ((size_t)b << 21) + ((size_t)(2 * y2) << 7) + xbase;
    for (int i = threadIdx.x; i < 1024; i += 256) {   // 2 rows x 16 slots x 32 xp-pairs
        int xp2 = (i & 31) << 1, slot = (i >> 5) & 15, row = i >> 9;
        const float* src = xp0 + ((size_t)(slot * 8) << 14) + (row << 7) + xp2;
        bf16x8 pk0, pk1;
#pragma unroll
        for (int j = 0; j < 8; ++j) {
            f32x2 v = *(const f32x2*)(src + ((size_t)j << 14));
            pk0[j] = (bf16)v[0];
            pk1[j] = (bf16)v[1];
        }
        *(bf16x8*)(t[row] + (xp2 << 7) + ((slot ^ (xp2 & 15)) << 3)) = pk0;
        *(bf16x8*)(t[row] + ((xp2 + 1) << 7) + ((slot ^ ((xp2 + 1) & 15)) << 3)) = pk1;
    }
    __syncthreads();
    bf16* ob = xb + ((((size_t)b << 7) + 2 * y2) << 14);
    for (int j = threadIdx.x; j < 2048; j += 256) {   // 2 rows x 64 xp x 16 slots
        int row = j >> 10, u = j & 1023;
        int xp = u >> 4, s = u & 15;
        *(bf16x8*)(ob + (row << 14) + ((xbase + xp) << 7) + (s << 3)) =
            *(bf16x8*)(t[row] + (xp << 7) + ((s ^ (xp & 15)) << 3));
    }
    bf16* tb = t0b + (((size_t)b * 64 + y2) << 13);   // row y2: 64 x2 * 128 c
    for (int u = threadIdx.x; u < 512; u += 256) {    // 32 x2 x 16 slots
        int s = u & 15, x2l = u >> 4;
        int xc0 = 2 * x2l, xc1 = 2 * x2l + 1;         // local tile columns
        bf16x8 va = *(bf16x8*)(t[0] + (xc0 << 7) + ((s ^ (xc0 & 15)) << 3));
        bf16x8 vb = *(bf16x8*)(t[0] + (xc1 << 7) + ((s ^ (xc1 & 15)) << 3));
        bf16x8 vc = *(bf16x8*)(t[1] + (xc0 << 7) + ((s ^ (xc0 & 15)) << 3));
        bf16x8 vd = *(bf16x8*)(t[1] + (xc1 << 7) + ((s ^ (xc1 & 15)) << 3));
        bf16x8 pk;
#pragma unroll
        for (int j = 0; j < 8; ++j)
            pk[j] = (bf16)(((float)va[j] + (float)vb[j] + (float)vc[j] + (float)vd[j]) * cf[s * 8 + j]);
        *(bf16x8*)(tb + (((xh << 5) + x2l) << 7) + (s << 3)) = pk;
    }
}

// ---------------------------------------------------------------------------
// MFMA implicit-GEMM 3x3 conv, Cin=128 -> Cout=64, stride 1, NHWC bf16 src.
// Block: 2 output rows x 32 cols x 64 co. Grid: (y_pairs, x_tiles, B).
// Waves: cg = wid&1 (co half), qg = wid>>1 (cin quarter). acc[2 co][4 pos].
// SWZY (K8): batch->XCD affinity decode — XCD = bx%8, choose b%8==bx%8 so
// each XCD's L2 holds only 4 batches' weights. Bijective (bx,bz)->(b,yp).
// ---------------------------------------------------------------------------
template<int PAD, bool PER_BATCH_W, bool LRELU, bool HAS_BIAS, bool SWZY, bool NHWC_OUT>
__global__ __launch_bounds__(512, 4) void k_conv_mfma(
    const bf16* __restrict__ src, const bf16* __restrict__ wgt,
    const float* __restrict__ bias, void* __restrict__ outp,
    int H, int W, int Hout, int Wout)
{
    __shared__ __align__(16) bf16 xs[4 * 34 * 128];   // 34816 B
    const int tid = threadIdx.x;
    const int wid = tid >> 6, lane = tid & 63;
    const int x0 = blockIdx.y << 5;
    const int bx = blockIdx.x;
    int b, y0;
    if (SWZY) {
        // grid (64, 2, 32): XCD = (bx + 64*by + 256*bz) % 8 = bx % 8.
        b  = (blockIdx.z & 24) | (bx & 7);            // b%8 == bx%8 -> XCD-local
        y0 = ((((bx >> 3) << 3) | (blockIdx.z & 7)) << 1);
    } else {
        b  = blockIdx.z;
        y0 = bx << 1;
    }

    // ---- wave constants + initial A prefetch (independent of LDS) ----
    const bf16* wb = wgt + (PER_BATCH_W ? ((size_t)b * 9 * 64 * 128) : 0);
    const int qg = wid >> 1;                     // cin quarter
    const int cg = wid & 1;                      // co half
    const int co0 = cg << 5;
    const int l15 = lane & 15, g = lane >> 4;
    const int q4g = (qg << 2) + g;
    const bf16* pA = wb + ((size_t)(co0 + l15) << 7) + (qg << 5) + (g << 3);
    bf16x8 A0 = *(const bf16x8*)(pA);
    bf16x8 A1 = *(const bf16x8*)(pA + (16 << 7));

    // ---- stage input tile [4 rows][34 cols][128 c] -> LDS (swizzled src) ----
    const bf16* sb = src + (((size_t)b * H) * W << 7);
    for (int k = tid; k < 4 * 34 * 16; k += 512) {
        int r = k / 544;
        int rem = k - r * 544;
        int c = rem >> 4, sp = rem & 15;
        int ys = y0 - PAD + r, xsrc = x0 - PAD + c;
        bf16x8 v = {};
        if (ys >= 0 && ys < H && xsrc >= 0 && xsrc < W)
            v = *(const bf16x8*)(sb + (((size_t)ys * W + xsrc) << 7) + ((sp ^ (c & 15)) << 3));
        *(bf16x8*)(xs + (k << 3)) = v;
    }
    __syncthreads();

    // ---- K-loop: 9 taps; per tap 2 A-loads (depth-1 prefetched) + 4 ds + 8 MFMA ----
    f32x4 acc[2][4] = {};
#pragma unroll
    for (int t = 0; t < 9; ++t) {
        bf16x8 A0n = A0, A1n = A1;
        if (t < 8) {
            A0n = *(const bf16x8*)(pA + ((size_t)(t + 1) << 13));
            A1n = *(const bf16x8*)(pA + ((size_t)(t + 1) << 13) + (16 << 7));
        }
        const int rt = t / 3, dx = t - 3 * rt;   // compile-time
        const int cb = l15 + dx;
        const int sl3 = (q4g ^ (cb & 15)) << 3;
#pragma unroll
        for (int rw = 0; rw < 2; ++rw) {
#pragma unroll
            for (int ch = 0; ch < 2; ++ch) {
                const int c0 = (ch << 4) + cb;
                bf16x8 bv = *(const bf16x8*)(xs + (((rw + rt) * 34 + c0) << 7) + sl3);
                const int n = (rw << 1) | ch;
                acc[0][n] = __builtin_amdgcn_mfma_f32_16x16x32_bf16(A0, bv, acc[0][n], 0, 0, 0);
                acc[1][n] = __builtin_amdgcn_mfma_f32_16x16x32_bf16(A1, bv, acc[1][n], 0, 0, 0);
            }
        }
        A0 = A0n; A1 = A1n;
    }

    // ---- 4-way K reduction via LDS (f32x4, [region][i][lane]) ----
    __syncthreads();                              // xs B-reads done
    f32x4* redv = (f32x4*)xs;                     // 32 KB of the 34816 B
    if (qg >= 2) {
        f32x4* wp = redv + (((cg << 1) | (qg - 2)) << 9) + lane;
#pragma unroll
        for (int m = 0; m < 2; ++m)
#pragma unroll
            for (int n = 0; n < 4; ++n)
                wp[(((m << 2) | n) << 6)] = acc[m][n];
    }
    __syncthreads();
    if (qg < 2) {
        const f32x4* rp = redv + (((cg << 1) | qg) << 9) + lane;
#pragma unroll
        for (int m = 0; m < 2; ++m)
#pragma unroll
            for (int n = 0; n < 4; ++n)
                acc[m][n] += rp[(((m << 2) | n) << 6)];
    }
    __syncthreads();
    if (qg == 1) {
        f32x4* wp = redv + (cg << 10) + lane;
#pragma unroll
        for (int m = 0; m < 2; ++m)
#pragma unroll
            for (int n = 0; n < 4; ++n)
                wp[(((m << 2) | n) << 6)] = acc[m][n];
    }
    __syncthreads();
    if (qg == 0) {
        const f32x4* rp = redv + (cg << 10) + lane;
#pragma unroll
        for (int m = 0; m < 2; ++m)
#pragma unroll
            for (int n = 0; n < 4; ++n)
                acc[m][n] += rp[(((m << 2) | n) << 6)];
        // ---- epilogue: col=lane&15 -> pos, row=g*4+reg -> co ----
#pragma unroll
        for (int m = 0; m < 2; ++m) {
#pragma unroll
            for (int n = 0; n < 4; ++n) {
                const int rw = n >> 1, ch = n & 1;
                const int xg = x0 + (ch << 4) + l15;
                const int yg = y0 + rw;
                if (xg < Wout && yg < Hout) {
                    if (NHWC_OUT) {
                        bf16x4 pk;
#pragma unroll
                        for (int reg = 0; reg < 4; ++reg) {
                            int co = co0 + m * 16 + (g << 2) + reg;
                            float v = acc[m][n][reg];
                            if (HAS_BIAS) v += bias[co];
                            if (LRELU) v = v >= 0.f ? v : 0.01f * v;
                            pk[reg] = (bf16)v;
                        }
                        *(bf16x4*)((bf16*)outp + ((((size_t)b * Hout + yg) * Wout + xg) << 6)
                                   + co0 + m * 16 + (g << 2)) = pk;
                    } else {
#pragma unroll
                        for (int reg = 0; reg < 4; ++reg) {
                            int co = co0 + m * 16 + (g << 2) + reg;
                            float v = acc[m][n][reg];
                            if (HAS_BIAS) v += bias[co];
                            if (LRELU) v = v >= 0.f ? v : 0.01f * v;
                            ((float*)outp)[(((size_t)b * 64 + co) * Hout + yg) * Wout + xg] = v;
                        }
                    }
                }
            }
        }
    }
}

// ---------------------------------------------------------------------------
// K4: MFMA conv 64cin->64co, k3, s2, p0. In t1b [b][62][62][64] bf16 NHWC,
// out t2b NHWC bf16 (32,30,30,64) + bias + lrelu.
// ---------------------------------------------------------------------------
__global__ __launch_bounds__(256) void k_conv_s2_mfma(
    const bf16* __restrict__ t1b, const bf16* __restrict__ w2b,
    const float* __restrict__ bias, bf16* __restrict__ t2b)
{
    __shared__ bf16 pl[2 * 3 * 33 * 64];        // E plane then O plane, 25344 B
    const int tid = threadIdx.x;
    const int wid = tid >> 6, lane = tid & 63;
    const int y0 = blockIdx.x, b = blockIdx.y;

    for (int k = tid; k < 1536; k += 256) {
        int sl = k & 7, xsc = (k >> 3) & 63, r = k >> 9;
        if (xsc < 62) {
            int iy = 2 * y0 + r;
            bf16x8 v = *(const bf16x8*)(t1b + (((size_t)b * 3844 + iy * 62 + xsc) << 6) + (sl << 3));
            int pcol = xsc >> 1;
            int dst = (xsc & 1) * 6336 + ((r * 33 + pcol) << 6) + ((sl ^ (pcol & 7)) << 3);
            *(bf16x8*)(pl + dst) = v;
        }
    }
    __syncthreads();

    const int co0 = wid << 4;
    const int l15 = lane & 15, g = lane >> 4;
    f32x4 acc[2] = {};

    for (int r = 0; r < 3; ++r) {
#pragma unroll
        for (int dx = 0; dx < 3; ++dx) {
            const bf16* wt = w2b + ((size_t)(r * 3 + dx) << 12);
            const int pbase = (dx == 1) ? 6336 : 0;
            const int cadd = (dx == 2) ? 1 : 0;
#pragma unroll
            for (int q = 0; q < 2; ++q) {
                bf16x8 a = *(const bf16x8*)(wt + ((co0 + l15) << 6) + (q << 5) + (g << 3));
#pragma unroll
                for (int n = 0; n < 2; ++n) {
                    int col = (n << 4) + l15 + cadd;
                    int sl = ((q << 2) + g) ^ (col & 7);
                    bf16x8 bf = *(const bf16x8*)(pl + pbase + ((r * 33 + col) << 6) + (sl << 3));
                    acc[n] = __builtin_amdgcn_mfma_f32_16x16x32_bf16(a, bf, acc[n], 0, 0, 0);
                }
            }
        }
    }

#pragma unroll
    for (int n = 0; n < 2; ++n) {
        int pos = (n << 4) + l15;
        if (pos < 30) {
            bf16x4 pk;
#pragma unroll
            for (int reg = 0; reg < 4; ++reg) {
                int co = co0 + (g << 2) + reg;
                float v = acc[n][reg] + bias[co];
                v = v >= 0.f ? v : 0.01f * v;
                pk[reg] = (bf16)v;
            }
            *(bf16x4*)(t2b + ((((size_t)b * 30 + y0) * 30 + pos) << 6) + co0 + (g << 2)) = pk;
        }
    }
}

// ---------------------------------------------------------------------------
// K5: MFMA conv 64cin->64co, k3, s2, p0. In t2b [b][30][30][64] bf16 NHWC,
// out t3 fp32 NCHW (32,64,14,14) + bias + lrelu. Planes [2][3][17][64].
// ---------------------------------------------------------------------------
__global__ __launch_bounds__(256) void k_conv3_s2_mfma(
    const bf16* __restrict__ t2b, const bf16* __restrict__ w3b,
    const float* __restrict__ bias, float* __restrict__ t3)
{
    __shared__ bf16 pl[2 * 3 * 17 * 64];        // 13056 B
    const int tid = threadIdx.x;
    const int wid = tid >> 6, lane = tid & 63;
    const int y0 = blockIdx.x, b = blockIdx.y;  // y0 in [0,14)

    for (int k = tid; k < 768; k += 256) {      // 3 r x 32 xsc x 8 sl
        int sl = k & 7, xsc = (k >> 3) & 31, r = k >> 8;
        if (xsc < 30) {
            int iy = 2 * y0 + r;
            bf16x8 v = *(const bf16x8*)(t2b + (((size_t)b * 900 + iy * 30 + xsc) << 6) + (sl << 3));
            int pcol = xsc >> 1;
            int dst = (xsc & 1) * 3264 + ((r * 17 + pcol) << 6) + ((sl ^ (pcol & 7)) << 3);
            *(bf16x8*)(pl + dst) = v;
        }
    }
    __syncthreads();

    const int co0 = wid << 4;
    const int l15 = lane & 15, g = lane >> 4;
    f32x4 acc = {};

    for (int r = 0; r < 3; ++r) {
#pragma unroll
        for (int dx = 0; dx < 3; ++dx) {
            const bf16* wt = w3b + ((size_t)(r * 3 + dx) << 12);
            const int pbase = (dx == 1) ? 3264 : 0;
            const int cadd = (dx == 2) ? 1 : 0;
#pragma unroll
            for (int q = 0; q < 2; ++q) {
                bf16x8 a = *(const bf16x8*)(wt + ((co0 + l15) << 6) + (q << 5) + (g << 3));
                int col = l15 + cadd;
                int sl = ((q << 2) + g) ^ (col & 7);
                bf16x8 bf = *(const bf16x8*)(pl + pbase + ((r * 17 + col) << 6) + (sl << 3));
                acc = __builtin_amdgcn_mfma_f32_16x16x32_bf16(a, bf, acc, 0, 0, 0);
            }
        }
    }

    if (l15 < 14) {
#pragma unroll
        for (int reg = 0; reg < 4; ++reg) {
            int co = co0 + (g << 2) + reg;
            float v = acc[reg] + bias[co];
            v = v >= 0.f ? v : 0.01f * v;
            t3[(((size_t)b * 64 + co) * 14 + y0) * 14 + l15] = v;
        }
    }
}

// Fused heads: mean_pos(conv(t,w)) = (1/36) sum_{cin,k} w[co,cin,k]*S[cin,k]
struct HeadPtrs { const float* w[5]; const float* b[5]; };

__global__ __launch_bounds__(256) void k_heads_fused(
    const float* __restrict__ t3, HeadPtrs hp,
    const float* __restrict__ att_fw, const float* __restrict__ att_fb,
    float* __restrict__ agg, float* __restrict__ katt)
{
    int b = blockIdx.x;
    __shared__ float S[576];
    __shared__ float ah[128];
    const float* tb = t3 + (size_t)b * 64 * 196;
    for (int i = threadIdx.x; i < 576; i += 256) {
        int ci = i / 9, k = i - ci * 9, kh = k / 3, kw = k - kh * 3;
        const float* tp = tb + ci * 196 + kh * 14 + kw;
        float s = 0.f;
#pragma unroll
        for (int oy = 0; oy < 6; ++oy)
#pragma unroll
            for (int ox = 0; ox < 6; ++ox) s += tp[oy * 28 + ox * 2];
        S[i] = s;
    }
    __syncthreads();
    for (int j = threadIdx.x; j < 640; j += 256) {
        int h = j >> 7, co = j & 127;
        const float* wp = hp.w[h] + (size_t)co * 576;
        float acc = 0.f;
        for (int k = 0; k < 576; ++k) acc += wp[k] * S[k];
        float v = acc * (1.f / 36.f) + hp.b[h][co];
        if (h < 4) agg[((size_t)b * 4 + h) * 128 + co] = v;
        else       ah[co] = v >= 0.f ? v : 0.01f * v;
    }
    __syncthreads();
    if (threadIdx.x < 4) {
        int e = threadIdx.x;
        float acc = att_fb[e];
        for (int j = 0; j < 128; ++j) acc += ah[j] * att_fw[e * 128 + j];
        katt[b * 4 + e] = acc;
    }
}

// wfinb[b][tap][co][cin] = bf16( coff[b,cin]*sum_e katt[b,e]*agg[b,e,cin]*ewr[e][tap][co][cin] )
__global__ __launch_bounds__(256) void k_combine(
    const float* __restrict__ ewr, const float* __restrict__ agg,
    const float* __restrict__ katt, const float* __restrict__ coff,
    bf16* __restrict__ wfinb)
{
    int i = blockIdx.x * 256 + threadIdx.x;   // 32*9*64*128 = 2359296 exact
    int cin = i & 127;
    int b   = i / (9 << 13);
    int tcc = i - b * (9 << 13);              // tap*8192 + co*128 + cin
    float s = 0.f;
#pragma unroll
    for (int e = 0; e < 4; ++e)
        s += katt[b * 4 + e] * agg[((size_t)b * 4 + e) * 128 + cin]
           * ewr[(size_t)e * (9 << 13) + tcc];    // coalesced: consecutive cin
    wfinb[i] = (bf16)(s * coff[b * 128 + cin]);
}

extern "C" void kernel_launch(void* const* d_in, const int* in_sizes, int n_in,
                              void* d_out, int out_size, void* d_ws, size_t ws_size,
                              hipStream_t stream) {
    const float* x      = (const float*)d_in[0];
    const float* wm     = (const float*)d_in[1];
    const float* wm_w1  = (const float*)d_in[2];
    const float* wm_b1  = (const float*)d_in[3];
    const float* wm_w2  = (const float*)d_in[4];
    const float* wm_b2  = (const float*)d_in[5];
    const float* tr_w1  = (const float*)d_in[6];
    const float* tr_b1  = (const float*)d_in[7];
    const float* tr_w2  = (const float*)d_in[8];
    const float* tr_b2  = (const float*)d_in[9];
    const float* tr_w3  = (const float*)d_in[10];
    const float* tr_b3  = (const float*)d_in[11];
    const float* t1_w   = (const float*)d_in[12];
    const float* t1_b   = (const float*)d_in[13];
    const float* t2_w   = (const float*)d_in[14];
    const float* t2_b   = (const float*)d_in[15];
    const float* t3_w   = (const float*)d_in[16];
    const float* t3_b   = (const float*)d_in[17];
    const float* t4_w   = (const float*)d_in[18];
    const float* t4_b   = (const float*)d_in[19];
    const float* att_cw = (const float*)d_in[20];
    const float* att_cb = (const float*)d_in[21];
    const float* att_fw = (const float*)d_in[22];
    const float* att_fb = (const float*)d_in[23];
    const float* expert_w = (const float*)d_in[24];
    float* out = (float*)d_out;

    // Workspace layout (float offsets; all 16B-aligned) — 194 MB (known good)
    float* ws = (float*)d_ws;
    float* wm_coff = ws;                       // 4096
    float* agg     = ws + 4096;                // 16384
    float* katt    = ws + 20480;               // 128
    bf16*  w1b     = (bf16*)(ws + 20736);      // 73728 bf16
    bf16*  w2b     = (bf16*)(ws + 57600);      // 36864 bf16
    bf16*  w3b     = (bf16*)(ws + 76032);      // 36864 bf16
    bf16*  wfinb   = (bf16*)(ws + 94464);      // 2359296 bf16
    bf16*  xb      = (bf16*)(ws + 1274112);    // 67108864 bf16 (32,128,128,128)
    bf16*  t0b     = (bf16*)(ws + 34828544);   // 16777216 bf16 (32,64,64,128)
    bf16*  t1b     = (bf16*)(ws + 43217152);   // 7872512 bf16  (32,62,62,64)
    bf16*  t2b     = (bf16*)(ws + 47153408);   // 1843200 bf16  (32,30,30,64)
    float* t3      = ws + 48075008;            // 401408        (32,64,14,14)
    // ewr (294912 fp32) ALIASES t1b region (3936256 floats) — t1b dead after K4
    float* ewr     = ws + 43217152;
    // total ~48.5M floats = ~194 MB

    // Kp: fused prep (wm MLP + 3 weight repacks)
    k_prep<<<608, 256, 0, stream>>>(wm, wm_w1, wm_b1, wm_w2, wm_b2, wm_coff,
                                    tr_w1, w1b, tr_w2, w2b, tr_w3, w3b);

    // Kxp: x -> NHWC bf16 + pooled/modulated t0b (x-split halves, 33KB LDS)
    k_x2nhwc_pool<<<dim3(128, 32), 256, 0, stream>>>(x, wm_coff, xb, t0b);

    // K3: MFMA conv1 128->64 s1 p0 (64x64 -> 62x62), bias+lrelu, NHWC bf16 out
    k_conv_mfma<0, false, true, true, false, true><<<dim3(31, 2, 32), 512, 0, stream>>>(
        t0b, w1b, tr_b1, (void*)t1b, 64, 64, 62, 62);

    // K4: MFMA conv2 64->64 s2 (62 -> 30), bias+lrelu, NHWC bf16 out
    k_conv_s2_mfma<<<dim3(30, 32), 256, 0, stream>>>(t1b, w2b, tr_b2, t2b);

    // Ke: expert_w repack into dead t1b space (294912 elems, 1152 blocks EXACT)
    k_ewr<<<1152, 256, 0, stream>>>(expert_w, ewr);

    // K5: MFMA conv3 64->64 s2 (30 -> 14), bias+lrelu, fp32 NCHW out
    k_conv3_s2_mfma<<<dim3(14, 32), 256, 0, stream>>>(t2b, w3b, tr_b3, t3);

    // K6: fused heads
    HeadPtrs hp;
    hp.w[0] = t1_w; hp.w[1] = t2_w; hp.w[2] = t3_w; hp.w[3] = t4_w; hp.w[4] = att_cw;
    hp.b[0] = t1_b; hp.b[1] = t2_b; hp.b[2] = t3_b; hp.b[3] = t4_b; hp.b[4] = att_cb;
    k_heads_fused<<<32, 256, 0, stream>>>(t3, hp, att_fw, att_fb, agg, katt);

    // K7: synthesize per-sample bf16 weights (coalesced ewr reads)
    k_combine<<<9216, 256, 0, stream>>>(ewr, agg, katt, wm_coff, wfinb);

    // K8: MFMA per-sample conv on xb, pad 1, batch->XCD affinity, fp32 NCHW out
    k_conv_mfma<1, true, false, false, true, false><<<dim3(64, 4, 32), 512, 0, stream>>>(
        xb, wfinb, nullptr, (void*)out, 128, 128, 128, 128);
}

// Round 26
// 426.456 us; speedup vs baseline: 1.0206x; 1.0206x over previous
//
#include <hip/hip_runtime.h>
#include <hip/hip_bf16.h>
#include <cstddef>
#include <cstdint>

typedef __bf16 bf16;
typedef __attribute__((ext_vector_type(8))) __bf16 bf16x8;
typedef __attribute__((ext_vector_type(4))) __bf16 bf16x4;
typedef __attribute__((ext_vector_type(4))) float f32x4;
typedef __attribute__((ext_vector_type(2))) float f32x2;

// ---------------------------------------------------------------------------
// FINAL (r24 champion, 427 us, 9.8x vs fp32 baseline):
//  Kp  fused prep: wm MLP -> wm_coff; tr_w1/2/3 -> w1b/w2b/w3b bf16 repacks
//  Kxp x NCHW fp32 -> xb NHWC bf16 + pooled/modulated t0b  [x-split 33KB LDS]
//  K3  MFMA conv 128->64 s1 p0 +bias+lrelu -> t1b NHWC bf16 (32,62,62,64)
//  K4  MFMA conv 64->64 s2 p0 +bias+lrelu -> t2b NHWC bf16 (32,30,30,64)
//  Ke  expert_w repack -> ewr[e][tap][co][cin] fp32 (294912 elems, 1152 blks)
//  K5  MFMA conv 64->64 s2 p0 +bias+lrelu -> t3 fp32 NCHW (32,64,14,14)
//  K6  fused heads (GAP trick) -> agg (32,4,128), katt (32,4)
//  K7  combine (coalesced ewr) + fold wm_coff -> wfinb bf16 [32][9][64][128]
//  K8  MFMA per-sample conv(xb, wfinb) p1 -> out fp32 NCHW (32,64,128,128)
// Settled constraints (measured): (512,4) launch bound — lower caps spill acc
// (r16: 910MB scratch); 34.8KB LDS — 48KB drops 4->3 blocks/CU (r18); y-pair
// XCD swizzle beats batch->XCD affinity (r25: input-halo reuse > weight reuse);
// K8 is a latency plateau at ~5x MFMA floor — 10 structural attacks null.
// ---------------------------------------------------------------------------

// Fused prep: blocks [0,288) w1b repack, [288,432) w2b, [432,576) w3b,
// [576,608) wm embedding MLP (threads 0..127 active).
__global__ __launch_bounds__(256) void k_prep(
    const float* __restrict__ wm, const float* __restrict__ wm_w1,
    const float* __restrict__ wm_b1, const float* __restrict__ wm_w2,
    const float* __restrict__ wm_b2, float* __restrict__ coff,
    const float* __restrict__ tr_w1, bf16* __restrict__ w1b,
    const float* __restrict__ tr_w2, bf16* __restrict__ w2b,
    const float* __restrict__ tr_w3, bf16* __restrict__ w3b)
{
    const int blk = blockIdx.x;
    if (blk < 288) {
        int i = blk * 256 + threadIdx.x;             // 73728 exact
        int cin = i & 127, t2 = i >> 7, co = t2 & 63, tap = t2 >> 6;
        w1b[i] = (bf16)(tr_w1[((size_t)co * 128 + cin) * 9 + tap]);
    } else if (blk < 432) {
        int i = (blk - 288) * 256 + threadIdx.x;     // 36864 exact
        int cin = i & 63, co = (i >> 6) & 63, tap = i >> 12;
        w2b[i] = (bf16)(tr_w2[((size_t)co * 64 + cin) * 9 + tap]);
    } else if (blk < 576) {
        int i = (blk - 432) * 256 + threadIdx.x;     // 36864 exact
        int cin = i & 63, co = (i >> 6) & 63, tap = i >> 12;
        w3b[i] = (bf16)(tr_w3[((size_t)co * 64 + cin) * 9 + tap]);
    } else {
        const int b = blk - 576;                     // 32 blocks
        __shared__ float h[128];
        const int j = threadIdx.x;
        if (j < 128) {
            float acc = wm_b1[j];
            for (int k = 0; k < 32; ++k) acc += wm[b * 32 + k] * wm_w1[j * 32 + k];
            h[j] = acc >= 0.f ? acc : 0.2f * acc;    // slope 0.2
        }
        __syncthreads();
        if (j < 128) {
            float acc2 = wm_b2[j];
            for (int k = 0; k < 128; ++k) acc2 += h[k] * wm_w2[j * 128 + k];
            coff[b * 128 + j] = acc2;
        }
    }
}

// expert_w [e][co][cin][tap] -> ewr [e][tap][co][cin]; 294912 elements EXACT.
__global__ __launch_bounds__(256) void k_ewr(
    const float* __restrict__ expert_w, float* __restrict__ ewr)
{
    int i = blockIdx.x * 256 + threadIdx.x;          // 1152 blocks * 256 = 294912
    int cin = i & 127;
    int co  = (i >> 7) & 63;
    int et  = i >> 13;                               // e*9 + tap, in [0,36)
    int tap = et % 9;
    int e   = et / 9;
    ewr[i] = expert_w[(((size_t)e * 64 + co) * 128 + cin) * 9 + tap];
}

// Fused: x [b][c][y][x] fp32 -> xb [b][y][x][c] bf16 (row pair, x-half) AND
// t0b for that (row pair, x-half). Tile [2 rows][64 xp][128 c] = 32 KB LDS.
__global__ __launch_bounds__(256) void k_x2nhwc_pool(
    const float* __restrict__ x, const float* __restrict__ coff,
    bf16* __restrict__ xb, bf16* __restrict__ t0b)
{
    __shared__ bf16 t[2][64 * 128];      // 32 KB, [row][xp_local][c] swizzled
    __shared__ float cf[128];
    const int y2 = blockIdx.x >> 1, xh = blockIdx.x & 1, b = blockIdx.y;
    const int xbase = xh << 6;           // x offset of this half-tile
    if (threadIdx.x < 128) cf[threadIdx.x] = 0.25f * coff[b * 128 + threadIdx.x];
    const float* xp0 = x + ((size_t)b << 21) + ((size_t)(2 * y2) << 7) + xbase;
    for (int i = threadIdx.x; i < 1024; i += 256) {   // 2 rows x 16 slots x 32 xp-pairs
        int xp2 = (i & 31) << 1, slot = (i >> 5) & 15, row = i >> 9;
        const float* src = xp0 + ((size_t)(slot * 8) << 14) + (row << 7) + xp2;
        bf16x8 pk0, pk1;
#pragma unroll
        for (int j = 0; j < 8; ++j) {
            f32x2 v = *(const f32x2*)(src + ((size_t)j << 14));
            pk0[j] = (bf16)v[0];
            pk1[j] = (bf16)v[1];
        }
        *(bf16x8*)(t[row] + (xp2 << 7) + ((slot ^ (xp2 & 15)) << 3)) = pk0;
        *(bf16x8*)(t[row] + ((xp2 + 1) << 7) + ((slot ^ ((xp2 + 1) & 15)) << 3)) = pk1;
    }
    __syncthreads();
    bf16* ob = xb + ((((size_t)b << 7) + 2 * y2) << 14);
    for (int j = threadIdx.x; j < 2048; j += 256) {   // 2 rows x 64 xp x 16 slots
        int row = j >> 10, u = j & 1023;
        int xp = u >> 4, s = u & 15;
        *(bf16x8*)(ob + (row << 14) + ((xbase + xp) << 7) + (s << 3)) =
            *(bf16x8*)(t[row] + (xp << 7) + ((s ^ (xp & 15)) << 3));
    }
    bf16* tb = t0b + (((size_t)b * 64 + y2) << 13);   // row y2: 64 x2 * 128 c
    for (int u = threadIdx.x; u < 512; u += 256) {    // 32 x2 x 16 slots
        int s = u & 15, x2l = u >> 4;
        int xc0 = 2 * x2l, xc1 = 2 * x2l + 1;         // local tile columns
        bf16x8 va = *(bf16x8*)(t[0] + (xc0 << 7) + ((s ^ (xc0 & 15)) << 3));
        bf16x8 vb = *(bf16x8*)(t[0] + (xc1 << 7) + ((s ^ (xc1 & 15)) << 3));
        bf16x8 vc = *(bf16x8*)(t[1] + (xc0 << 7) + ((s ^ (xc0 & 15)) << 3));
        bf16x8 vd = *(bf16x8*)(t[1] + (xc1 << 7) + ((s ^ (xc1 & 15)) << 3));
        bf16x8 pk;
#pragma unroll
        for (int j = 0; j < 8; ++j)
            pk[j] = (bf16)(((float)va[j] + (float)vb[j] + (float)vc[j] + (float)vd[j]) * cf[s * 8 + j]);
        *(bf16x8*)(tb + (((xh << 5) + x2l) << 7) + (s << 3)) = pk;
    }
}

// ---------------------------------------------------------------------------
// MFMA implicit-GEMM 3x3 conv, Cin=128 -> Cout=64, stride 1, NHWC bf16 src.
// Block: 2 output rows x 32 cols x 64 co. Grid: (y_pairs, x_tiles, B).
// Waves: cg = wid&1 (co half), qg = wid>>1 (cin quarter). acc[2 co][4 pos]
// with pos n = (rw<<1)|ch: row y0+rw, col x0+ch*16+l15.
// Depth-1 A-prefetch; initial A-loads issued above the staging barrier.
// ---------------------------------------------------------------------------
template<int PAD, bool PER_BATCH_W, bool LRELU, bool HAS_BIAS, bool SWZY, bool NHWC_OUT>
__global__ __launch_bounds__(512, 4) void k_conv_mfma(
    const bf16* __restrict__ src, const bf16* __restrict__ wgt,
    const float* __restrict__ bias, void* __restrict__ outp,
    int H, int W, int Hout, int Wout)
{
    __shared__ __align__(16) bf16 xs[4 * 34 * 128];   // 34816 B
    const int tid = threadIdx.x;
    const int wid = tid >> 6, lane = tid & 63;
    const int b = blockIdx.z;
    const int x0 = blockIdx.y << 5;
    int bx = blockIdx.x;
    // XCD swizzle (gridDim.x == 64): 8 consecutive y-pairs (16 rows) per XCD
    const int yp = SWZY ? (((bx & 7) << 3) | (bx >> 3)) : bx;
    const int y0 = yp << 1;

    // ---- wave constants + initial A prefetch (independent of LDS) ----
    const bf16* wb = wgt + (PER_BATCH_W ? ((size_t)b * 9 * 64 * 128) : 0);
    const int qg = wid >> 1;                     // cin quarter
    const int cg = wid & 1;                      // co half
    const int co0 = cg << 5;
    const int l15 = lane & 15, g = lane >> 4;
    const int q4g = (qg << 2) + g;
    const bf16* pA = wb + ((size_t)(co0 + l15) << 7) + (qg << 5) + (g << 3);
    bf16x8 A0 = *(const bf16x8*)(pA);
    bf16x8 A1 = *(const bf16x8*)(pA + (16 << 7));

    // ---- stage input tile [4 rows][34 cols][128 c] -> LDS (swizzled src) ----
    const bf16* sb = src + (((size_t)b * H) * W << 7);
    for (int k = tid; k < 4 * 34 * 16; k += 512) {
        int r = k / 544;
        int rem = k - r * 544;
        int c = rem >> 4, sp = rem & 15;
        int ys = y0 - PAD + r, xsrc = x0 - PAD + c;
        bf16x8 v = {};
        if (ys >= 0 && ys < H && xsrc >= 0 && xsrc < W)
            v = *(const bf16x8*)(sb + (((size_t)ys * W + xsrc) << 7) + ((sp ^ (c & 15)) << 3));
        *(bf16x8*)(xs + (k << 3)) = v;
    }
    __syncthreads();

    // ---- K-loop: 9 taps; per tap 2 A-loads (depth-1 prefetched) + 4 ds + 8 MFMA ----
    f32x4 acc[2][4] = {};
#pragma unroll
    for (int t = 0; t < 9; ++t) {
        bf16x8 A0n = A0, A1n = A1;
        if (t < 8) {
            A0n = *(const bf16x8*)(pA + ((size_t)(t + 1) << 13));
            A1n = *(const bf16x8*)(pA + ((size_t)(t + 1) << 13) + (16 << 7));
        }
        const int rt = t / 3, dx = t - 3 * rt;   // compile-time
        const int cb = l15 + dx;
        const int sl3 = (q4g ^ (cb & 15)) << 3;
#pragma unroll
        for (int rw = 0; rw < 2; ++rw) {
#pragma unroll
            for (int ch = 0; ch < 2; ++ch) {
                const int c0 = (ch << 4) + cb;
                bf16x8 bv = *(const bf16x8*)(xs + (((rw + rt) * 34 + c0) << 7) + sl3);
                const int n = (rw << 1) | ch;
                acc[0][n] = __builtin_amdgcn_mfma_f32_16x16x32_bf16(A0, bv, acc[0][n], 0, 0, 0);
                acc[1][n] = __builtin_amdgcn_mfma_f32_16x16x32_bf16(A1, bv, acc[1][n], 0, 0, 0);
            }
        }
        A0 = A0n; A1 = A1n;
    }

    // ---- 4-way K reduction via LDS (f32x4, [region][i][lane]) ----
    __syncthreads();                              // xs B-reads done
    f32x4* redv = (f32x4*)xs;                     // 32 KB of the 34816 B
    if (qg >= 2) {
        f32x4* wp = redv + (((cg << 1) | (qg - 2)) << 9) + lane;
#pragma unroll
        for (int m = 0; m < 2; ++m)
#pragma unroll
            for (int n = 0; n < 4; ++n)
                wp[(((m << 2) | n) << 6)] = acc[m][n];
    }
    __syncthreads();
    if (qg < 2) {
        const f32x4* rp = redv + (((cg << 1) | qg) << 9) + lane;
#pragma unroll
        for (int m = 0; m < 2; ++m)
#pragma unroll
            for (int n = 0; n < 4; ++n)
                acc[m][n] += rp[(((m << 2) | n) << 6)];
    }
    __syncthreads();
    if (qg == 1) {
        f32x4* wp = redv + (cg << 10) + lane;
#pragma unroll
        for (int m = 0; m < 2; ++m)
#pragma unroll
            for (int n = 0; n < 4; ++n)
                wp[(((m << 2) | n) << 6)] = acc[m][n];
    }
    __syncthreads();
    if (qg == 0) {
        const f32x4* rp = redv + (cg << 10) + lane;
#pragma unroll
        for (int m = 0; m < 2; ++m)
#pragma unroll
            for (int n = 0; n < 4; ++n)
                acc[m][n] += rp[(((m << 2) | n) << 6)];
        // ---- epilogue: col=lane&15 -> pos, row=g*4+reg -> co ----
#pragma unroll
        for (int m = 0; m < 2; ++m) {
#pragma unroll
            for (int n = 0; n < 4; ++n) {
                const int rw = n >> 1, ch = n & 1;
                const int xg = x0 + (ch << 4) + l15;
                const int yg = y0 + rw;
                if (xg < Wout && yg < Hout) {
                    if (NHWC_OUT) {
                        bf16x4 pk;
#pragma unroll
                        for (int reg = 0; reg < 4; ++reg) {
                            int co = co0 + m * 16 + (g << 2) + reg;
                            float v = acc[m][n][reg];
                            if (HAS_BIAS) v += bias[co];
                            if (LRELU) v = v >= 0.f ? v : 0.01f * v;
                            pk[reg] = (bf16)v;
                        }
                        *(bf16x4*)((bf16*)outp + ((((size_t)b * Hout + yg) * Wout + xg) << 6)
                                   + co0 + m * 16 + (g << 2)) = pk;
                    } else {
#pragma unroll
                        for (int reg = 0; reg < 4; ++reg) {
                            int co = co0 + m * 16 + (g << 2) + reg;
                            float v = acc[m][n][reg];
                            if (HAS_BIAS) v += bias[co];
                            if (LRELU) v = v >= 0.f ? v : 0.01f * v;
                            ((float*)outp)[(((size_t)b * 64 + co) * Hout + yg) * Wout + xg] = v;
                        }
                    }
                }
            }
        }
    }
}

// ---------------------------------------------------------------------------
// K4: MFMA conv 64cin->64co, k3, s2, p0. In t1b [b][62][62][64] bf16 NHWC,
// out t2b NHWC bf16 (32,30,30,64) + bias + lrelu.
// ---------------------------------------------------------------------------
__global__ __launch_bounds__(256) void k_conv_s2_mfma(
    const bf16* __restrict__ t1b, const bf16* __restrict__ w2b,
    const float* __restrict__ bias, bf16* __restrict__ t2b)
{
    __shared__ bf16 pl[2 * 3 * 33 * 64];        // E plane then O plane, 25344 B
    const int tid = threadIdx.x;
    const int wid = tid >> 6, lane = tid & 63;
    const int y0 = blockIdx.x, b = blockIdx.y;

    for (int k = tid; k < 1536; k += 256) {
        int sl = k & 7, xsc = (k >> 3) & 63, r = k >> 9;
        if (xsc < 62) {
            int iy = 2 * y0 + r;
            bf16x8 v = *(const bf16x8*)(t1b + (((size_t)b * 3844 + iy * 62 + xsc) << 6) + (sl << 3));
            int pcol = xsc >> 1;
            int dst = (xsc & 1) * 6336 + ((r * 33 + pcol) << 6) + ((sl ^ (pcol & 7)) << 3);
            *(bf16x8*)(pl + dst) = v;
        }
    }
    __syncthreads();

    const int co0 = wid << 4;
    const int l15 = lane & 15, g = lane >> 4;
    f32x4 acc[2] = {};

    for (int r = 0; r < 3; ++r) {
#pragma unroll
        for (int dx = 0; dx < 3; ++dx) {
            const bf16* wt = w2b + ((size_t)(r * 3 + dx) << 12);
            const int pbase = (dx == 1) ? 6336 : 0;
            const int cadd = (dx == 2) ? 1 : 0;
#pragma unroll
            for (int q = 0; q < 2; ++q) {
                bf16x8 a = *(const bf16x8*)(wt + ((co0 + l15) << 6) + (q << 5) + (g << 3));
#pragma unroll
                for (int n = 0; n < 2; ++n) {
                    int col = (n << 4) + l15 + cadd;
                    int sl = ((q << 2) + g) ^ (col & 7);
                    bf16x8 bf = *(const bf16x8*)(pl + pbase + ((r * 33 + col) << 6) + (sl << 3));
                    acc[n] = __builtin_amdgcn_mfma_f32_16x16x32_bf16(a, bf, acc[n], 0, 0, 0);
                }
            }
        }
    }

#pragma unroll
    for (int n = 0; n < 2; ++n) {
        int pos = (n << 4) + l15;
        if (pos < 30) {
            bf16x4 pk;
#pragma unroll
            for (int reg = 0; reg < 4; ++reg) {
                int co = co0 + (g << 2) + reg;
                float v = acc[n][reg] + bias[co];
                v = v >= 0.f ? v : 0.01f * v;
                pk[reg] = (bf16)v;
            }
            *(bf16x4*)(t2b + ((((size_t)b * 30 + y0) * 30 + pos) << 6) + co0 + (g << 2)) = pk;
        }
    }
}

// ---------------------------------------------------------------------------
// K5: MFMA conv 64cin->64co, k3, s2, p0. In t2b [b][30][30][64] bf16 NHWC,
// out t3 fp32 NCHW (32,64,14,14) + bias + lrelu. Planes [2][3][17][64].
// ---------------------------------------------------------------------------
__global__ __launch_bounds__(256) void k_conv3_s2_mfma(
    const bf16* __restrict__ t2b, const bf16* __restrict__ w3b,
    const float* __restrict__ bias, float* __restrict__ t3)
{
    __shared__ bf16 pl[2 * 3 * 17 * 64];        // 13056 B
    const int tid = threadIdx.x;
    const int wid = tid >> 6, lane = tid & 63;
    const int y0 = blockIdx.x, b = blockIdx.y;  // y0 in [0,14)

    for (int k = tid; k < 768; k += 256) {      // 3 r x 32 xsc x 8 sl
        int sl = k & 7, xsc = (k >> 3) & 31, r = k >> 8;
        if (xsc < 30) {
            int iy = 2 * y0 + r;
            bf16x8 v = *(const bf16x8*)(t2b + (((size_t)b * 900 + iy * 30 + xsc) << 6) + (sl << 3));
            int pcol = xsc >> 1;
            int dst = (xsc & 1) * 3264 + ((r * 17 + pcol) << 6) + ((sl ^ (pcol & 7)) << 3);
            *(bf16x8*)(pl + dst) = v;
        }
    }
    __syncthreads();

    const int co0 = wid << 4;
    const int l15 = lane & 15, g = lane >> 4;
    f32x4 acc = {};

    for (int r = 0; r < 3; ++r) {
#pragma unroll
        for (int dx = 0; dx < 3; ++dx) {
            const bf16* wt = w3b + ((size_t)(r * 3 + dx) << 12);
            const int pbase = (dx == 1) ? 3264 : 0;
            const int cadd = (dx == 2) ? 1 : 0;
#pragma unroll
            for (int q = 0; q < 2; ++q) {
                bf16x8 a = *(const bf16x8*)(wt + ((co0 + l15) << 6) + (q << 5) + (g << 3));
                int col = l15 + cadd;
                int sl = ((q << 2) + g) ^ (col & 7);
                bf16x8 bf = *(const bf16x8*)(pl + pbase + ((r * 17 + col) << 6) + (sl << 3));
                acc = __builtin_amdgcn_mfma_f32_16x16x32_bf16(a, bf, acc, 0, 0, 0);
            }
        }
    }

    if (l15 < 14) {
#pragma unroll
        for (int reg = 0; reg < 4; ++reg) {
            int co = co0 + (g << 2) + reg;
            float v = acc[reg] + bias[co];
            v = v >= 0.f ? v : 0.01f * v;
            t3[(((size_t)b * 64 + co) * 14 + y0) * 14 + l15] = v;
        }
    }
}

// Fused heads: mean_pos(conv(t,w)) = (1/36) sum_{cin,k} w[co,cin,k]*S[cin,k]
struct HeadPtrs { const float* w[5]; const float* b[5]; };

__global__ __launch_bounds__(256) void k_heads_fused(
    const float* __restrict__ t3, HeadPtrs hp,
    const float* __restrict__ att_fw, const float* __restrict__ att_fb,
    float* __restrict__ agg, float* __restrict__ katt)
{
    int b = blockIdx.x;
    __shared__ float S[576];
    __shared__ float ah[128];
    const float* tb = t3 + (size_t)b * 64 * 196;
    for (int i = threadIdx.x; i < 576; i += 256) {
        int ci = i / 9, k = i - ci * 9, kh = k / 3, kw = k - kh * 3;
        const float* tp = tb + ci * 196 + kh * 14 + kw;
        float s = 0.f;
#pragma unroll
        for (int oy = 0; oy < 6; ++oy)
#pragma unroll
            for (int ox = 0; ox < 6; ++ox) s += tp[oy * 28 + ox * 2];
        S[i] = s;
    }
    __syncthreads();
    for (int j = threadIdx.x; j < 640; j += 256) {
        int h = j >> 7, co = j & 127;
        const float* wp = hp.w[h] + (size_t)co * 576;
        float acc = 0.f;
        for (int k = 0; k < 576; ++k) acc += wp[k] * S[k];
        float v = acc * (1.f / 36.f) + hp.b[h][co];
        if (h < 4) agg[((size_t)b * 4 + h) * 128 + co] = v;
        else       ah[co] = v >= 0.f ? v : 0.01f * v;
    }
    __syncthreads();
    if (threadIdx.x < 4) {
        int e = threadIdx.x;
        float acc = att_fb[e];
        for (int j = 0; j < 128; ++j) acc += ah[j] * att_fw[e * 128 + j];
        katt[b * 4 + e] = acc;
    }
}

// wfinb[b][tap][co][cin] = bf16( coff[b,cin]*sum_e katt[b,e]*agg[b,e,cin]*ewr[e][tap][co][cin] )
__global__ __launch_bounds__(256) void k_combine(
    const float* __restrict__ ewr, const float* __restrict__ agg,
    const float* __restrict__ katt, const float* __restrict__ coff,
    bf16* __restrict__ wfinb)
{
    int i = blockIdx.x * 256 + threadIdx.x;   // 32*9*64*128 = 2359296 exact
    int cin = i & 127;
    int b   = i / (9 << 13);
    int tcc = i - b * (9 << 13);              // tap*8192 + co*128 + cin
    float s = 0.f;
#pragma unroll
    for (int e = 0; e < 4; ++e)
        s += katt[b * 4 + e] * agg[((size_t)b * 4 + e) * 128 + cin]
           * ewr[(size_t)e * (9 << 13) + tcc];    // coalesced: consecutive cin
    wfinb[i] = (bf16)(s * coff[b * 128 + cin]);
}

extern "C" void kernel_launch(void* const* d_in, const int* in_sizes, int n_in,
                              void* d_out, int out_size, void* d_ws, size_t ws_size,
                              hipStream_t stream) {
    const float* x      = (const float*)d_in[0];
    const float* wm     = (const float*)d_in[1];
    const float* wm_w1  = (const float*)d_in[2];
    const float* wm_b1  = (const float*)d_in[3];
    const float* wm_w2  = (const float*)d_in[4];
    const float* wm_b2  = (const float*)d_in[5];
    const float* tr_w1  = (const float*)d_in[6];
    const float* tr_b1  = (const float*)d_in[7];
    const float* tr_w2  = (const float*)d_in[8];
    const float* tr_b2  = (const float*)d_in[9];
    const float* tr_w3  = (const float*)d_in[10];
    const float* tr_b3  = (const float*)d_in[11];
    const float* t1_w   = (const float*)d_in[12];
    const float* t1_b   = (const float*)d_in[13];
    const float* t2_w   = (const float*)d_in[14];
    const float* t2_b   = (const float*)d_in[15];
    const float* t3_w   = (const float*)d_in[16];
    const float* t3_b   = (const float*)d_in[17];
    const float* t4_w   = (const float*)d_in[18];
    const float* t4_b   = (const float*)d_in[19];
    const float* att_cw = (const float*)d_in[20];
    const float* att_cb = (const float*)d_in[21];
    const float* att_fw = (const float*)d_in[22];
    const float* att_fb = (const float*)d_in[23];
    const float* expert_w = (const float*)d_in[24];
    float* out = (float*)d_out;

    // Workspace layout (float offsets; all 16B-aligned) — 194 MB (known good)
    float* ws = (float*)d_ws;
    float* wm_coff = ws;                       // 4096
    float* agg     = ws + 4096;                // 16384
    float* katt    = ws + 20480;               // 128
    bf16*  w1b     = (bf16*)(ws + 20736);      // 73728 bf16
    bf16*  w2b     = (bf16*)(ws + 57600);      // 36864 bf16
    bf16*  w3b     = (bf16*)(ws + 76032);      // 36864 bf16
    bf16*  wfinb   = (bf16*)(ws + 94464);      // 2359296 bf16
    bf16*  xb      = (bf16*)(ws + 1274112);    // 67108864 bf16 (32,128,128,128)
    bf16*  t0b     = (bf16*)(ws + 34828544);   // 16777216 bf16 (32,64,64,128)
    bf16*  t1b     = (bf16*)(ws + 43217152);   // 7872512 bf16  (32,62,62,64)
    bf16*  t2b     = (bf16*)(ws + 47153408);   // 1843200 bf16  (32,30,30,64)
    float* t3      = ws + 48075008;            // 401408        (32,64,14,14)
    // ewr (294912 fp32) ALIASES t1b region (3936256 floats) — t1b dead after K4
    float* ewr     = ws + 43217152;
    // total ~48.5M floats = ~194 MB

    // Kp: fused prep (wm MLP + 3 weight repacks)
    k_prep<<<608, 256, 0, stream>>>(wm, wm_w1, wm_b1, wm_w2, wm_b2, wm_coff,
                                    tr_w1, w1b, tr_w2, w2b, tr_w3, w3b);

    // Kxp: x -> NHWC bf16 + pooled/modulated t0b (x-split halves, 33KB LDS)
    k_x2nhwc_pool<<<dim3(128, 32), 256, 0, stream>>>(x, wm_coff, xb, t0b);

    // K3: MFMA conv1 128->64 s1 p0 (64x64 -> 62x62), bias+lrelu, NHWC bf16 out
    k_conv_mfma<0, false, true, true, false, true><<<dim3(31, 2, 32), 512, 0, stream>>>(
        t0b, w1b, tr_b1, (void*)t1b, 64, 64, 62, 62);

    // K4: MFMA conv2 64->64 s2 (62 -> 30), bias+lrelu, NHWC bf16 out
    k_conv_s2_mfma<<<dim3(30, 32), 256, 0, stream>>>(t1b, w2b, tr_b2, t2b);

    // Ke: expert_w repack into dead t1b space (294912 elems, 1152 blocks EXACT)
    k_ewr<<<1152, 256, 0, stream>>>(expert_w, ewr);

    // K5: MFMA conv3 64->64 s2 (30 -> 14), bias+lrelu, fp32 NCHW out
    k_conv3_s2_mfma<<<dim3(14, 32), 256, 0, stream>>>(t2b, w3b, tr_b3, t3);

    // K6: fused heads
    HeadPtrs hp;
    hp.w[0] = t1_w; hp.w[1] = t2_w; hp.w[2] = t3_w; hp.w[3] = t4_w; hp.w[4] = att_cw;
    hp.b[0] = t1_b; hp.b[1] = t2_b; hp.b[2] = t3_b; hp.b[3] = t4_b; hp.b[4] = att_cb;
    k_heads_fused<<<32, 256, 0, stream>>>(t3, hp, att_fw, att_fb, agg, katt);

    // K7: synthesize per-sample bf16 weights (coalesced ewr reads)
    k_combine<<<9216, 256, 0, stream>>>(ewr, agg, katt, wm_coff, wfinb);

    // K8: MFMA per-sample conv on xb, pad 1, y-pair XCD swizzle, fp32 NCHW out
    k_conv_mfma<1, true, false, false, true, false><<<dim3(64, 4, 32), 512, 0, stream>>>(
        xb, wfinb, nullptr, (void*)out, 128, 128, 128, 128);
}